// Round 18
// baseline (582.798 us; speedup 1.0000x reference)
//
#include <hip/hip_runtime.h>
#include <math.h>

// UniMP / TransformerConv block. bf16-MFMA GEMMs (LDS-transposed coalesced epilogue),
// single-pass flash-style edge phase (2 waves/node + LDS online-softmax merge,
// unroll-2 + 1-deep software pipeline, float2-packed VALU), fused tail (8-wave).
//   alpha = q_s.k + ea.qe_s + q_s.be   (scale 1/sqrt(D) folded into Wq/WqeT/bqe)
//   agg   = sum attn*v[src] + (sum attn*ea) @ We_h + be_h
// Node tensors: qs_bf bf16 [n][512] = skip, kvq bf16 [n][2048] = [q|k|v|qe]

typedef short bf16x8 __attribute__((ext_vector_type(8)));
typedef unsigned short u16x8 __attribute__((ext_vector_type(8)));
typedef float f32x4 __attribute__((ext_vector_type(4)));
typedef float fv4 __attribute__((ext_vector_type(4)));   // native vec for nontemporal builtins
typedef float f32x2 __attribute__((ext_vector_type(2)));
typedef unsigned int u32x4 __attribute__((ext_vector_type(4)));

#define SCALE 0.08838834764831845f  // 1/sqrt(128)

__device__ inline unsigned short f2bf(float f) {
    union { float f; unsigned u; } v; v.f = f;
    unsigned r = (v.u + 0x7FFFu + ((v.u >> 16) & 1u)) >> 16;
    return (unsigned short)r;
}
__device__ inline float bf2f(unsigned short u) {
    union { unsigned u; float f; } v; v.u = ((unsigned)u) << 16; return v.f;
}
__device__ inline fv4 ntload4(const float* p) {
    return __builtin_nontemporal_load((const fv4*)p);
}
// one u32 holding 2 bf16 (little-endian: low half = even element) -> f32x2
__device__ inline f32x2 bfpair2f(unsigned u) {
    union { unsigned u; float f; } lo, hi;
    lo.u = u << 16; hi.u = u & 0xffff0000u;
    f32x2 r; r[0] = lo.f; r[1] = hi.f; return r;
}

// ---------------- K0: WqeT = s*Wq@We^T (LDS-tiled); bqe; zero deg ----------------
// blocks 0..63: (m-tile, c-tile, head); block 64: bqe; blocks 65+: deg zero
__global__ __launch_bounds__(256) void wqe_k(
    const float* __restrict__ Wq, const float* __restrict__ bq,
    const float* __restrict__ We,
    float* __restrict__ WqeT, float* __restrict__ bqe,
    int* __restrict__ deg, int n)
{
    const int b = blockIdx.x, t = threadIdx.x;
    if (b < 64) {
        const int mt = b & 3, ct = (b >> 2) & 3, h = b >> 4;
        const int m0 = mt * 32, c0 = ct * 32;
        __shared__ float aq[32][129];
        __shared__ float awe[32][129];
        for (int i = t; i < 32 * 32; i += 256) {        // 32 rows x 32 float4 chunks
            int r = i >> 5, ch = i & 31;
            float4 v = *(const float4*)&Wq[(size_t)(m0 + r) * 512 + h * 128 + ch * 4];
            *(float4*)&aq[r][ch * 4] = v;
            float4 w = *(const float4*)&We[(size_t)(c0 + r) * 512 + h * 128 + ch * 4];
            *(float4*)&awe[r][ch * 4] = w;
        }
        __syncthreads();
        const int ty = t >> 4, tx = t & 15;
        float acc[2][2] = {};
        #pragma unroll 4
        for (int d = 0; d < 128; ++d) {
            float a0 = aq[ty * 2][d], a1 = aq[ty * 2 + 1][d];
            float b0 = awe[tx * 2][d], b1 = awe[tx * 2 + 1][d];
            acc[0][0] += a0 * b0; acc[0][1] += a0 * b1;
            acc[1][0] += a1 * b0; acc[1][1] += a1 * b1;
        }
        #pragma unroll
        for (int i = 0; i < 2; ++i)
            #pragma unroll
            for (int j = 0; j < 2; ++j)
                WqeT[(size_t)(m0 + ty * 2 + i) * 512 + h * 128 + c0 + tx * 2 + j] = acc[i][j] * SCALE;
    } else if (b == 64) {
        __shared__ float bqs[512];
        for (int i = t; i < 512; i += 256) bqs[i] = bq[i];
        __syncthreads();
        for (int hc = t; hc < 512; hc += 256) {
            const int h = hc >> 7, c = hc & 127;
            const float* we = &We[(size_t)c * 512 + h * 128];
            const float* bb = &bqs[h * 128];
            float s = 0.f;
            #pragma unroll 8
            for (int d = 0; d < 128; ++d) s += bb[d] * we[d];
            bqe[hc] = s * SCALE;
        }
    } else {
        int idx = (b - 65) * 256 + t;
        if (idx < n) deg[idx] = 0;
    }
}

// ---------------- K0b: bf16 conversions + fragment layouts + deg_count ----------------
__global__ __launch_bounds__(256) void prep_k(
    const float* __restrict__ x,
    const float* __restrict__ Wq, const float* __restrict__ bq,
    const float* __restrict__ Wk, const float* __restrict__ bk,
    const float* __restrict__ Wv, const float* __restrict__ bv,
    const float* __restrict__ Ws, const float* __restrict__ bs,
    const float* __restrict__ WqeT, const float* __restrict__ bqe,
    const float* __restrict__ We, const float* __restrict__ Wlin,
    unsigned short* __restrict__ x_bf, unsigned short* __restrict__ Wfrag,
    unsigned short* __restrict__ Wefrag, unsigned short* __restrict__ Wlfrag,
    float* __restrict__ bcat,
    const int* __restrict__ ei, int* __restrict__ deg, int E, int n, int nb1)
{
    const int b = blockIdx.x, t = threadIdx.x;
    if (b < nb1) {                                  // x -> bf16, 4 elems/thread
        int i = (b * 256 + t) * 4;
        if (i < n * 128) {
            float4 v = *(const float4*)&x[i];
            unsigned short o[4] = { f2bf(v.x), f2bf(v.y), f2bf(v.z), f2bf(v.w) };
            *(uint2*)&x_bf[i] = *(uint2*)o;
        }
    } else if (b < nb1 + 160) {                     // Wfrag: [q|k|v|skip|qe] 128x2560
        int g = (b - nb1) * 256 + t;                // (nt*4+kt)*64+lane, nt<160
        int lane = g & 63, kt = (g >> 6) & 3, nt = g >> 8;
        int ncol = nt * 16 + (lane & 15);
        int k0 = kt * 32 + ((lane >> 4) << 3);
        const float* W; int c; float sc = 1.f;
        if      (ncol < 512)  { W = Wq;   c = ncol; sc = SCALE; }
        else if (ncol < 1024) { W = Wk;   c = ncol - 512; }
        else if (ncol < 1536) { W = Wv;   c = ncol - 1024; }
        else if (ncol < 2048) { W = Ws;   c = ncol - 1536; }
        else                  { W = WqeT; c = ncol - 2048; }
        unsigned short o[8];
        #pragma unroll
        for (int j = 0; j < 8; ++j) o[j] = f2bf(W[(size_t)(k0 + j) * 512 + c] * sc);
        *(uint4*)&Wfrag[(size_t)g * 8] = *(uint4*)o;
    } else if (b < nb1 + 192) {                     // Wefrag: We 128x512
        int g = (b - nb1 - 160) * 256 + t;          // nt<32, kt<4
        int lane = g & 63, kt = (g >> 6) & 3, nt = g >> 8;
        int ncol = nt * 16 + (lane & 15);
        int k0 = kt * 32 + ((lane >> 4) << 3);
        unsigned short o[8];
        #pragma unroll
        for (int j = 0; j < 8; ++j) o[j] = f2bf(We[(size_t)(k0 + j) * 512 + ncol]);
        *(uint4*)&Wefrag[(size_t)g * 8] = *(uint4*)o;
    } else if (b < nb1 + 224) {                     // Wlfrag: Wlin 512x128
        int g = (b - nb1 - 192) * 256 + t;          // (nt*16+kt)*64+lane, nt<8, kt<16
        int lane = g & 63, kt = (g >> 6) & 15, nt = g >> 10;
        int ncol = nt * 16 + (lane & 15);
        int k0 = kt * 32 + ((lane >> 4) << 3);
        unsigned short o[8];
        #pragma unroll
        for (int j = 0; j < 8; ++j) o[j] = f2bf(Wlin[(size_t)(k0 + j) * 128 + ncol]);
        *(uint4*)&Wlfrag[(size_t)g * 8] = *(uint4*)o;
    } else if (b < nb1 + 234) {                     // bcat[2560]
        int c = (b - nb1 - 224) * 256 + t;
        if (c < 2560)
            bcat[c] = (c < 512) ? bq[c] * SCALE : (c < 1024) ? bk[c - 512]
                     : (c < 1536) ? bv[c - 1024] : (c < 2048) ? bs[c - 1536] : bqe[c - 2048];
    } else {                                        // deg_count
        int e = (b - nb1 - 234) * 256 + t;
        if (e < E) atomicAdd(&deg[ei[E + e]], 1);
    }
}

// ---------------- K2: exclusive scan of deg -> row_start, cursor ----------------
__global__ __launch_bounds__(1024) void scan_k(const int* __restrict__ deg,
                                               int* __restrict__ row_start,
                                               int* __restrict__ cursor, int n)
{
    __shared__ int part[1024];
    const int t = threadIdx.x;
    const int c0 = t * 16;                  // supports n <= 16384
    int loc[16];
    int s = 0;
    #pragma unroll
    for (int i = 0; i < 16; ++i) {
        int idx = c0 + i;
        int dv = (idx < n) ? deg[idx] : 0;
        loc[i] = s; s += dv;
    }
    part[t] = s;
    __syncthreads();
    int incl = s;
    for (int off = 1; off < 1024; off <<= 1) {
        int other = (t >= off) ? part[t - off] : 0;
        __syncthreads();
        incl += other;
        part[t] = incl;
        __syncthreads();
    }
    const int base = incl - s;
    #pragma unroll
    for (int i = 0; i < 16; ++i) {
        int idx = c0 + i;
        if (idx < n) { row_start[idx] = base + loc[i]; cursor[idx] = base + loc[i]; }
    }
    if (t == 1023) row_start[n] = incl;
}

// ---------------- K3: node GEMM (bf16 MFMA) + LDS-transposed coalesced epilogue ----------
// skip -> qs_bf bf16 [n][512]; q,k,v,qe -> kvq bf16 [n][2048]. + CSR scatter slice (by==40)
__global__ __launch_bounds__(256) void node_gemm_mfma(
    const unsigned short* __restrict__ x_bf, const unsigned short* __restrict__ Wfrag,
    const float* __restrict__ bcat, unsigned short* __restrict__ qs_bf,
    unsigned short* __restrict__ kvq,
    const int* __restrict__ ei, int* __restrict__ cursor, int2* __restrict__ csr,
    int E, int n)
{
    if (blockIdx.y == 40) {                         // scatter slice
        const int nth = gridDim.x * 256;
        for (int e = blockIdx.x * 256 + threadIdx.x; e < E; e += nth) {
            int dnode = ei[E + e];
            int p = atomicAdd(&cursor[dnode], 1);
            csr[p] = make_int2(e, ei[e]);           // (eid, src)
        }
        return;
    }
    __shared__ float tile[64][68];                  // f32 block tile, +4 pad
    const int t = threadIdx.x, lane = t & 63, w = t >> 6;
    const int bm = blockIdx.x * 64;
    const int by = blockIdx.y;
    const int m0 = (w >> 1) * 32;                   // wave-local row base
    const int n0 = (w & 1) * 32;                    // wave-local col base
    const int lr = lane & 15, lk = (lane >> 4) << 3;
    f32x4 acc[2][2] = {};
    #pragma unroll
    for (int kt = 0; kt < 4; ++kt) {
        bf16x8 a[2], bf[2];
        #pragma unroll
        for (int mi = 0; mi < 2; ++mi) {
            int row = bm + m0 + mi * 16 + lr; row = row < n ? row : n - 1;
            a[mi] = *(const bf16x8*)&x_bf[(size_t)row * 128 + kt * 32 + lk];
        }
        #pragma unroll
        for (int ni = 0; ni < 2; ++ni) {
            int nt = (by * 64 + n0 + ni * 16) >> 4;
            bf[ni] = *(const bf16x8*)&Wfrag[(size_t)((nt * 4 + kt) * 64 + lane) * 8];
        }
        #pragma unroll
        for (int mi = 0; mi < 2; ++mi)
            #pragma unroll
            for (int ni = 0; ni < 2; ++ni)
                acc[mi][ni] = __builtin_amdgcn_mfma_f32_16x16x32_bf16(a[mi], bf[ni], acc[mi][ni], 0, 0, 0);
    }
    // stage D-fragments to LDS (layout: col=lane&15, row=(lane>>4)*4+j)
    #pragma unroll
    for (int mi = 0; mi < 2; ++mi)
        #pragma unroll
        for (int j = 0; j < 4; ++j)
            #pragma unroll
            for (int ni = 0; ni < 2; ++ni)
                tile[m0 + mi * 16 + (lane >> 4) * 4 + j][n0 + ni * 16 + lr] = acc[mi][ni][j];
    __syncthreads();
    // coalesced store: thread t -> row r=t>>2, 16 consecutive cols at (t&3)*16
    const int r = t >> 2, cs = (t & 3) * 16;
    const int row = bm + r;
    if (row < n) {
        const int colg0 = by * 64 + cs;
        unsigned short o[16];
        #pragma unroll
        for (int i = 0; i < 16; ++i) o[i] = f2bf(tile[r][cs + i] + bcat[colg0 + i]);
        unsigned short* dst;
        if (by < 24)      dst = &kvq[(size_t)row * 2048 + colg0];            // q,k,v
        else if (by < 32) dst = &qs_bf[(size_t)row * 512 + (colg0 - 1536)];  // skip
        else              dst = &kvq[(size_t)row * 2048 + (colg0 - 512)];    // qe
        *(uint4*)dst = *(uint4*)o;
        *(uint4*)(dst + 8) = *(uint4*)&o[8];
    }
}

// ---------------- K5: flash-style edge phase, 2 waves/node + LDS merge ----------------
// unroll-2 + 1-deep software pipeline; float2-packed math (v_pk_fma_f32);
// non-temporal ea loads (streamed once). launch_bounds min 8 waves/EU (residency probe).
__global__ __launch_bounds__(256, 8) void edge_k(
    const unsigned short* __restrict__ kvq, const float* __restrict__ ea,
    const float* __restrict__ be,
    const int* __restrict__ row_start, const int2* __restrict__ csr,
    unsigned short* __restrict__ wsum_bf, unsigned short* __restrict__ vacc_bf, int n)
{
    const int t = threadIdx.x, lane = t & 63, w = t >> 6;
    const int slot = w >> 1, half = w & 1;
    const int node = blockIdx.x * 2 + slot;
    const bool nvalid = node < n;
    const int nodec = nvalid ? node : 0;
    const int g = lane >> 4;            // head
    const int l15 = lane & 15;
    const int sl = l15 * 8;             // dim slice within head

    __shared__ float lds_m[2][4], lds_den[2][4];
    __shared__ float lds_va[2][4][128], lds_ws[2][4][128];

    int rs = 0, deg = 0;
    if (nvalid) { rs = row_start[node]; deg = row_start[node + 1] - rs; }
    const int dh = (deg + 1) >> 1;
    const int lo = half ? dh : 0;
    const int myc = half ? (deg - dh) : dh;

    // per-lane q_s, qe_s as f32x2 pairs (pre-scaled, from bf16)
    f32x2 q2[4], qe2[4];
    {
        const u32x4 uq  = *(const u32x4*)&kvq[(size_t)nodec * 2048 + g * 128 + sl];
        const u32x4 uqe = *(const u32x4*)&kvq[(size_t)nodec * 2048 + 1536 + g * 128 + sl];
        #pragma unroll
        for (int j = 0; j < 4; ++j) { q2[j] = bfpair2f(uq[j]); qe2[j] = bfpair2f(uqe[j]); }
    }
    float qbe;
    {
        const f32x2* bp = (const f32x2*)&be[g * 128 + sl];
        f32x2 pb2 = q2[0] * bp[0] + q2[1] * bp[1] + q2[2] * bp[2] + q2[3] * bp[3];
        float pb = pb2[0] + pb2[1];
        #pragma unroll
        for (int o = 1; o <= 8; o <<= 1) pb += __shfl_xor(pb, o);
        qbe = pb;
    }

    float m = -3.0e38f, den = 0.f;
    f32x2 va2[4] = {}, ws2[4] = {};

    for (int j0 = 0; j0 < myc; j0 += 64) {
        const int cnt = min(64, myc - j0);
        int2 my = make_int2(0, 0);
        if (lane < cnt) my = csr[rs + lo + j0 + lane];

        // ---- preload pair 0 (current register set)
        fv4 cA0, cB0, cA1, cB1; u32x4 cK0, cV0, cK1, cV1;
        {
            const int i1 = (1 < cnt) ? 1 : 0;
            const int e0 = __shfl(my.x, 0), s0_ = __shfl(my.y, 0);
            const int e1 = __shfl(my.x, i1), s1_ = __shfl(my.y, i1);
            const float* ep0 = &ea[(size_t)e0 * 128 + sl];
            const float* ep1 = &ea[(size_t)e1 * 128 + sl];
            cA0 = ntload4(ep0); cB0 = ntload4(ep0 + 4);
            cA1 = ntload4(ep1); cB1 = ntload4(ep1 + 4);
            cK0 = *(const u32x4*)&kvq[(size_t)s0_ * 2048 + 512 + g * 128 + sl];
            cV0 = *(const u32x4*)&kvq[(size_t)s0_ * 2048 + 1024 + g * 128 + sl];
            cK1 = *(const u32x4*)&kvq[(size_t)s1_ * 2048 + 512 + g * 128 + sl];
            cV1 = *(const u32x4*)&kvq[(size_t)s1_ * 2048 + 1024 + g * 128 + sl];
        }

        for (int jj = 0; jj < cnt; jj += 2) {
            // ---- issue next pair's loads (hide latency under current compute)
            fv4 nA0, nB0, nA1, nB1; u32x4 nK0, nV0, nK1, nV1;
            {
                const int nj = (jj + 2 < cnt) ? jj + 2 : jj;        // clamped; unused on exit
                const int i1 = (nj + 1 < cnt) ? nj + 1 : nj;
                const int e0 = __shfl(my.x, nj), s0_ = __shfl(my.y, nj);
                const int e1 = __shfl(my.x, i1), s1_ = __shfl(my.y, i1);
                const float* ep0 = &ea[(size_t)e0 * 128 + sl];
                const float* ep1 = &ea[(size_t)e1 * 128 + sl];
                nA0 = ntload4(ep0); nB0 = ntload4(ep0 + 4);
                nA1 = ntload4(ep1); nB1 = ntload4(ep1 + 4);
                nK0 = *(const u32x4*)&kvq[(size_t)s0_ * 2048 + 512 + g * 128 + sl];
                nV0 = *(const u32x4*)&kvq[(size_t)s0_ * 2048 + 1024 + g * 128 + sl];
                nK1 = *(const u32x4*)&kvq[(size_t)s1_ * 2048 + 512 + g * 128 + sl];
                nV1 = *(const u32x4*)&kvq[(size_t)s1_ * 2048 + 1024 + g * 128 + sl];
            }
            // ---- compute with current pair (float2-packed)
            const bool two = (jj + 1 < cnt);
            f32x2 ef0[4], ef1[4], kf0[4], kf1[4];
            ef0[0][0]=cA0.x; ef0[0][1]=cA0.y; ef0[1][0]=cA0.z; ef0[1][1]=cA0.w;
            ef0[2][0]=cB0.x; ef0[2][1]=cB0.y; ef0[3][0]=cB0.z; ef0[3][1]=cB0.w;
            ef1[0][0]=cA1.x; ef1[0][1]=cA1.y; ef1[1][0]=cA1.z; ef1[1][1]=cA1.w;
            ef1[2][0]=cB1.x; ef1[2][1]=cB1.y; ef1[3][0]=cB1.z; ef1[3][1]=cB1.w;
            #pragma unroll
            for (int j = 0; j < 4; ++j) { kf0[j] = bfpair2f(cK0[j]); kf1[j] = bfpair2f(cK1[j]); }
            f32x2 acc0 = {0.f, 0.f}, acc1 = {0.f, 0.f};
            #pragma unroll
            for (int j = 0; j < 4; ++j) {
                acc0 += q2[j] * kf0[j] + qe2[j] * ef0[j];
                acc1 += q2[j] * kf1[j] + qe2[j] * ef1[j];
            }
            float p0 = acc0[0] + acc0[1];
            float p1 = acc1[0] + acc1[1];
            #pragma unroll
            for (int o = 1; o <= 8; o <<= 1) {
                p0 += __shfl_xor(p0, o);
                p1 += __shfl_xor(p1, o);
            }
            const float a0 = p0 + qbe;
            const float a1 = two ? (p1 + qbe) : -3.0e38f;   // dummy tail: weight 0
            // group-max batched online update (deferred-max THR=8)
            const float gm = fmaxf(a0, a1);
            if (gm > m + 8.f) {
                const float sc = __expf(m - gm);
                den *= sc;
                #pragma unroll
                for (int j = 0; j < 4; ++j) { va2[j] *= sc; ws2[j] *= sc; }
                m = gm;
            }
            const float w0 = __expf(a0 - m);
            const float w1 = __expf(a1 - m);
            den += w0 + w1;
            #pragma unroll
            for (int j = 0; j < 4; ++j) {
                va2[j] += bfpair2f(cV0[j]) * w0 + bfpair2f(cV1[j]) * w1;
                ws2[j] += ef0[j] * w0 + ef1[j] * w1;
            }
            // ---- rotate pipeline registers
            cA0 = nA0; cB0 = nB0; cA1 = nA1; cB1 = nB1;
            cK0 = nK0; cV0 = nV0; cK1 = nK1; cV1 = nV1;
        }
    }

    // merge halves: half 1 publishes, half 0 combines and writes out
    if (half == 1) {
        if (l15 == 0) { lds_m[slot][g] = m; lds_den[slot][g] = den; }
        #pragma unroll
        for (int j = 0; j < 4; ++j) {
            *(f32x2*)&lds_va[slot][g][sl + 2 * j] = va2[j];
            *(f32x2*)&lds_ws[slot][g][sl + 2 * j] = ws2[j];
        }
    }
    __syncthreads();
    if (half == 0 && nvalid) {
        const float m1 = lds_m[slot][g], den1 = lds_den[slot][g];
        const float M = fmaxf(m, m1);
        const float s0 = __expf(m - M), s1 = __expf(m1 - M);
        const float dtot = den * s0 + den1 * s1;
        const float rden = (dtot > 0.f) ? 1.f / dtot : 0.f;
        unsigned short vo[8], wo[8];
        #pragma unroll
        for (int j = 0; j < 4; ++j) {
            f32x2 ov = (va2[j] * s0 + *(const f32x2*)&lds_va[slot][g][sl + 2 * j] * s1) * rden;
            f32x2 ow = (ws2[j] * s0 + *(const f32x2*)&lds_ws[slot][g][sl + 2 * j] * s1) * rden;
            vo[2 * j] = f2bf(ov[0]); vo[2 * j + 1] = f2bf(ov[1]);
            wo[2 * j] = f2bf(ow[0]); wo[2 * j + 1] = f2bf(ow[1]);
        }
        *(uint4*)&vacc_bf[(size_t)node * 512 + g * 128 + sl] = *(uint4*)vo;
        *(uint4*)&wsum_bf[(size_t)node * 512 + g * 128 + sl] = *(uint4*)wo;
    }
}

// ---------------- K6: fused tail (8 waves): y = vacc + wsum@We_h + hb*be + skip; LN;
// out-GEMM; ELU. 16 rows/block. Stage 1: wave (h=w&3, half=w>>2) computes 4 ni-tiles of
// head h. Stage 2: wave w computes out cols [w*16, w*16+16).
__global__ __launch_bounds__(512) void tail_k(
    const unsigned short* __restrict__ wsum_bf, const unsigned short* __restrict__ Wefrag,
    const float* __restrict__ be, const unsigned short* __restrict__ vacc_bf,
    const unsigned short* __restrict__ qs_bf, const int* __restrict__ row_start,
    const unsigned short* __restrict__ Wlfrag, const float* __restrict__ lng,
    const float* __restrict__ lnb, const float* __restrict__ blin,
    const float* __restrict__ x, float* __restrict__ out, int n)
{
    const int t = threadIdx.x, lane = t & 63, w = t >> 6;
    const int h = w & 3, hf = w >> 2;               // stage-1 head, ni-half
    const int r0 = blockIdx.x * 16;
    const int lr = lane & 15, lk = (lane >> 4) << 3;
    __shared__ unsigned short nlds[16][520];        // normed bf16, +8 pad (16B-aligned rows)
    __shared__ float red_s[8][16], red_q[8][16], mval[16], rval[16];

    // ---- stage 1: wave (h,hf) computes 16 rows x 64 cols (head h, ni in [hf*4, hf*4+4))
    f32x4 acc[4] = {};
    #pragma unroll
    for (int kt = 0; kt < 4; ++kt) {
        int row = r0 + lr; row = row < n ? row : n - 1;
        bf16x8 a = *(const bf16x8*)&wsum_bf[(size_t)row * 512 + h * 128 + kt * 32 + lk];
        #pragma unroll
        for (int ni = 0; ni < 4; ++ni) {
            bf16x8 bfr = *(const bf16x8*)&Wefrag[(size_t)(((h * 8 + hf * 4 + ni) * 4 + kt) * 64 + lane) * 8];
            acc[ni] = __builtin_amdgcn_mfma_f32_16x16x32_bf16(a, bfr, acc[ni], 0, 0, 0);
        }
    }
    float g8[4], b8[4];
    #pragma unroll
    for (int ni = 0; ni < 4; ++ni) {
        int col = h * 128 + (hf * 4 + ni) * 16 + lr;
        g8[ni] = lng[col]; b8[ni] = lnb[col];
    }
    float sum_[4], sq_[4];
    #pragma unroll
    for (int j = 0; j < 4; ++j) {
        int row = r0 + (lane >> 4) * 4 + j;
        int rowc = row < n ? row : n - 1;
        const float hb = (row_start[rowc + 1] > row_start[rowc]) ? 1.f : 0.f;
        float s = 0.f, q = 0.f;
        #pragma unroll
        for (int ni = 0; ni < 4; ++ni) {
            int col = h * 128 + (hf * 4 + ni) * 16 + lr;
            float y = acc[ni][j] + bf2f(vacc_bf[(size_t)rowc * 512 + col]) + hb * be[col]
                    + bf2f(qs_bf[(size_t)rowc * 512 + col]);
            acc[ni][j] = y;
            s += y; q += y * y;
        }
        sum_[j] = s; sq_[j] = q;
    }
    #pragma unroll
    for (int o = 1; o <= 8; o <<= 1) {
        #pragma unroll
        for (int j = 0; j < 4; ++j) { sum_[j] += __shfl_xor(sum_[j], o); sq_[j] += __shfl_xor(sq_[j], o); }
    }
    if (lr == 0) {
        #pragma unroll
        for (int j = 0; j < 4; ++j) {
            red_s[w][(lane >> 4) * 4 + j] = sum_[j];
            red_q[w][(lane >> 4) * 4 + j] = sq_[j];
        }
    }
    __syncthreads();
    if (t < 16) {
        float S = 0.f, Q = 0.f;
        #pragma unroll
        for (int i = 0; i < 8; ++i) { S += red_s[i][t]; Q += red_q[i][t]; }
        float mu = S * (1.f / 512.f);
        float var = Q * (1.f / 512.f) - mu * mu;
        mval[t] = mu;
        rval[t] = rsqrtf(fmaxf(var, 0.f) + 1e-5f);
    }
    __syncthreads();
    #pragma unroll
    for (int j = 0; j < 4; ++j) {
        int rowl = (lane >> 4) * 4 + j;
        float mu = mval[rowl], rv = rval[rowl];
        #pragma unroll
        for (int ni = 0; ni < 4; ++ni) {
            int col = h * 128 + (hf * 4 + ni) * 16 + lr;
            nlds[rowl][col] = f2bf((acc[ni][j] - mu) * rv * g8[ni] + b8[ni]);
        }
    }
    __syncthreads();
    // ---- stage 2: out = elu(nlds @ Wlin + blin + x), wave w covers cols [w*16, w*16+16)
    f32x4 acc2 = {};
    #pragma unroll
    for (int kt = 0; kt < 16; ++kt) {
        bf16x8 a2 = *(const bf16x8*)&nlds[lr][kt * 32 + lk];
        bf16x8 bfr = *(const bf16x8*)&Wlfrag[(size_t)((w * 16 + kt) * 64 + lane) * 8];
        acc2 = __builtin_amdgcn_mfma_f32_16x16x32_bf16(a2, bfr, acc2, 0, 0, 0);
    }
    #pragma unroll
    for (int j = 0; j < 4; ++j) {
        int row = r0 + (lane >> 4) * 4 + j;
        if (row < n) {
            int col = w * 16 + lr;
            float z = acc2[j] + blin[col] + x[(size_t)row * 128 + col];
            out[(size_t)row * 128 + col] = z > 0.f ? z : expm1f(z);
        }
    }
}

extern "C" void kernel_launch(void* const* d_in, const int* in_sizes, int n_in,
                              void* d_out, int out_size, void* d_ws, size_t ws_size,
                              hipStream_t stream)
{
    const float* x   = (const float*)d_in[0];
    const int*   ei  = (const int*)d_in[1];
    const float* ea  = (const float*)d_in[2];
    const float* Wq  = (const float*)d_in[3];
    const float* bq  = (const float*)d_in[4];
    const float* Wk  = (const float*)d_in[5];
    const float* bk  = (const float*)d_in[6];
    const float* Wv  = (const float*)d_in[7];
    const float* bv  = (const float*)d_in[8];
    const float* We  = (const float*)d_in[9];
    const float* be  = (const float*)d_in[10];
    const float* Wsk = (const float*)d_in[11];
    const float* bsk = (const float*)d_in[12];
    const float* lng = (const float*)d_in[13];
    const float* lnb = (const float*)d_in[14];
    const float* Wl  = (const float*)d_in[15];
    const float* bl  = (const float*)d_in[16];
    float* out = (float*)d_out;

    const int n = in_sizes[0] / 128;
    const int E = in_sizes[1] / 2;

    float* WqeT  = (float*)d_ws;                    // 128*512
    float* bqe   = WqeT + 128 * 512;                // 512
    float* bcat  = bqe + 512;                       // 2560
    unsigned short* x_bf    = (unsigned short*)(bcat + 2560);   // n*128
    unsigned short* qs_bf   = x_bf + (size_t)n * 128;           // n*512 (skip)
    unsigned short* wsum_bf = qs_bf + (size_t)n * 512;          // n*512
    unsigned short* vacc_bf = wsum_bf + (size_t)n * 512;        // n*512
    unsigned short* kvq     = vacc_bf + (size_t)n * 512;        // n*2048 (q|k|v|qe)
    unsigned short* Wfrag   = kvq + (size_t)n * 2048;           // 128*2560
    unsigned short* Wefrag  = Wfrag + 128 * 2560;               // 128*512
    unsigned short* Wlfrag  = Wefrag + 128 * 512;               // 512*128
    int2* csr = (int2*)(((uintptr_t)(Wlfrag + 512 * 128) + 7) & ~(uintptr_t)7);  // E pairs
    int* deg       = (int*)(csr + E);
    int* row_start = deg + n;
    int* cursor    = row_start + n + 1;

    const int ndegb = (n + 255) / 256;
    wqe_k<<<65 + ndegb, 256, 0, stream>>>(Wq, bq, We, WqeT, bqe, deg, n);
    const int nb1 = (n * 32 + 255) / 256;           // x-conversion blocks (4 elems/thread)
    const int ndc = (E + 255) / 256;
    prep_k<<<nb1 + 234 + ndc, 256, 0, stream>>>(x, Wq, bq, Wk, bk, Wv, bv, Wsk, bsk, WqeT, bqe,
                                                We, Wl, x_bf, Wfrag, Wefrag, Wlfrag, bcat,
                                                ei, deg, E, n, nb1);
    scan_k<<<1, 1024, 0, stream>>>(deg, row_start, cursor, n);
    dim3 g1((n + 63) / 64, 41);
    node_gemm_mfma<<<g1, 256, 0, stream>>>(x_bf, Wfrag, bcat, qs_bf, kvq, ei, cursor, csr, E, n);
    edge_k<<<(n + 1) / 2, 256, 0, stream>>>(kvq, ea, be, row_start, csr,
                                            wsum_bf, vacc_bf, n);
    tail_k<<<(n + 15) / 16, 512, 0, stream>>>(wsum_bf, Wefrag, be, vacc_bf, qs_bf, row_start,
                                              Wlfrag, lng, lnb, bl, x, out, n);
}

// Round 19
// 169.459 us; speedup vs baseline: 3.4392x; 3.4392x over previous
//
#include <hip/hip_runtime.h>
#include <math.h>

// UniMP / TransformerConv block. bf16-MFMA GEMMs (LDS-transposed coalesced epilogue),
// single-pass flash-style edge phase (2 waves/node + LDS online-softmax merge,
// unroll-2 + 1-deep software pipeline, float2-packed VALU), fused tail (8-wave).
//   alpha = q_s.k + ea.qe_s + q_s.be   (scale 1/sqrt(D) folded into Wq/WqeT/bqe)
//   agg   = sum attn*v[src] + (sum attn*ea) @ We_h + be_h
// Node tensors: qs_bf bf16 [n][512] = skip, kvq bf16 [n][2048] = [q|k|v|qe]

typedef short bf16x8 __attribute__((ext_vector_type(8)));
typedef unsigned short u16x8 __attribute__((ext_vector_type(8)));
typedef float f32x4 __attribute__((ext_vector_type(4)));
typedef float fv4 __attribute__((ext_vector_type(4)));   // native vec for nontemporal builtins
typedef float f32x2 __attribute__((ext_vector_type(2)));
typedef unsigned int u32x4 __attribute__((ext_vector_type(4)));

#define SCALE 0.08838834764831845f  // 1/sqrt(128)

__device__ inline unsigned short f2bf(float f) {
    union { float f; unsigned u; } v; v.f = f;
    unsigned r = (v.u + 0x7FFFu + ((v.u >> 16) & 1u)) >> 16;
    return (unsigned short)r;
}
__device__ inline float bf2f(unsigned short u) {
    union { unsigned u; float f; } v; v.u = ((unsigned)u) << 16; return v.f;
}
__device__ inline fv4 ntload4(const float* p) {
    return __builtin_nontemporal_load((const fv4*)p);
}
// one u32 holding 2 bf16 (little-endian: low half = even element) -> f32x2
__device__ inline f32x2 bfpair2f(unsigned u) {
    union { unsigned u; float f; } lo, hi;
    lo.u = u << 16; hi.u = u & 0xffff0000u;
    f32x2 r; r[0] = lo.f; r[1] = hi.f; return r;
}

// ---------------- K0: WqeT = s*Wq@We^T (LDS-tiled); bqe; zero deg ----------------
// blocks 0..63: (m-tile, c-tile, head); block 64: bqe; blocks 65+: deg zero
__global__ __launch_bounds__(256) void wqe_k(
    const float* __restrict__ Wq, const float* __restrict__ bq,
    const float* __restrict__ We,
    float* __restrict__ WqeT, float* __restrict__ bqe,
    int* __restrict__ deg, int n)
{
    const int b = blockIdx.x, t = threadIdx.x;
    if (b < 64) {
        const int mt = b & 3, ct = (b >> 2) & 3, h = b >> 4;
        const int m0 = mt * 32, c0 = ct * 32;
        __shared__ float aq[32][129];
        __shared__ float awe[32][129];
        for (int i = t; i < 32 * 32; i += 256) {        // 32 rows x 32 float4 chunks
            int r = i >> 5, ch = i & 31;
            float4 v = *(const float4*)&Wq[(size_t)(m0 + r) * 512 + h * 128 + ch * 4];
            *(float4*)&aq[r][ch * 4] = v;
            float4 w = *(const float4*)&We[(size_t)(c0 + r) * 512 + h * 128 + ch * 4];
            *(float4*)&awe[r][ch * 4] = w;
        }
        __syncthreads();
        const int ty = t >> 4, tx = t & 15;
        float acc[2][2] = {};
        #pragma unroll 4
        for (int d = 0; d < 128; ++d) {
            float a0 = aq[ty * 2][d], a1 = aq[ty * 2 + 1][d];
            float b0 = awe[tx * 2][d], b1 = awe[tx * 2 + 1][d];
            acc[0][0] += a0 * b0; acc[0][1] += a0 * b1;
            acc[1][0] += a1 * b0; acc[1][1] += a1 * b1;
        }
        #pragma unroll
        for (int i = 0; i < 2; ++i)
            #pragma unroll
            for (int j = 0; j < 2; ++j)
                WqeT[(size_t)(m0 + ty * 2 + i) * 512 + h * 128 + c0 + tx * 2 + j] = acc[i][j] * SCALE;
    } else if (b == 64) {
        __shared__ float bqs[512];
        for (int i = t; i < 512; i += 256) bqs[i] = bq[i];
        __syncthreads();
        for (int hc = t; hc < 512; hc += 256) {
            const int h = hc >> 7, c = hc & 127;
            const float* we = &We[(size_t)c * 512 + h * 128];
            const float* bb = &bqs[h * 128];
            float s = 0.f;
            #pragma unroll 8
            for (int d = 0; d < 128; ++d) s += bb[d] * we[d];
            bqe[hc] = s * SCALE;
        }
    } else {
        int idx = (b - 65) * 256 + t;
        if (idx < n) deg[idx] = 0;
    }
}

// ---------------- K0b: bf16 conversions + fragment layouts + deg_count ----------------
__global__ __launch_bounds__(256) void prep_k(
    const float* __restrict__ x,
    const float* __restrict__ Wq, const float* __restrict__ bq,
    const float* __restrict__ Wk, const float* __restrict__ bk,
    const float* __restrict__ Wv, const float* __restrict__ bv,
    const float* __restrict__ Ws, const float* __restrict__ bs,
    const float* __restrict__ WqeT, const float* __restrict__ bqe,
    const float* __restrict__ We, const float* __restrict__ Wlin,
    unsigned short* __restrict__ x_bf, unsigned short* __restrict__ Wfrag,
    unsigned short* __restrict__ Wefrag, unsigned short* __restrict__ Wlfrag,
    float* __restrict__ bcat,
    const int* __restrict__ ei, int* __restrict__ deg, int E, int n, int nb1)
{
    const int b = blockIdx.x, t = threadIdx.x;
    if (b < nb1) {                                  // x -> bf16, 4 elems/thread
        int i = (b * 256 + t) * 4;
        if (i < n * 128) {
            float4 v = *(const float4*)&x[i];
            unsigned short o[4] = { f2bf(v.x), f2bf(v.y), f2bf(v.z), f2bf(v.w) };
            *(uint2*)&x_bf[i] = *(uint2*)o;
        }
    } else if (b < nb1 + 160) {                     // Wfrag: [q|k|v|skip|qe] 128x2560
        int g = (b - nb1) * 256 + t;                // (nt*4+kt)*64+lane, nt<160
        int lane = g & 63, kt = (g >> 6) & 3, nt = g >> 8;
        int ncol = nt * 16 + (lane & 15);
        int k0 = kt * 32 + ((lane >> 4) << 3);
        const float* W; int c; float sc = 1.f;
        if      (ncol < 512)  { W = Wq;   c = ncol; sc = SCALE; }
        else if (ncol < 1024) { W = Wk;   c = ncol - 512; }
        else if (ncol < 1536) { W = Wv;   c = ncol - 1024; }
        else if (ncol < 2048) { W = Ws;   c = ncol - 1536; }
        else                  { W = WqeT; c = ncol - 2048; }
        unsigned short o[8];
        #pragma unroll
        for (int j = 0; j < 8; ++j) o[j] = f2bf(W[(size_t)(k0 + j) * 512 + c] * sc);
        *(uint4*)&Wfrag[(size_t)g * 8] = *(uint4*)o;
    } else if (b < nb1 + 192) {                     // Wefrag: We 128x512
        int g = (b - nb1 - 160) * 256 + t;          // nt<32, kt<4
        int lane = g & 63, kt = (g >> 6) & 3, nt = g >> 8;
        int ncol = nt * 16 + (lane & 15);
        int k0 = kt * 32 + ((lane >> 4) << 3);
        unsigned short o[8];
        #pragma unroll
        for (int j = 0; j < 8; ++j) o[j] = f2bf(We[(size_t)(k0 + j) * 512 + ncol]);
        *(uint4*)&Wefrag[(size_t)g * 8] = *(uint4*)o;
    } else if (b < nb1 + 224) {                     // Wlfrag: Wlin 512x128
        int g = (b - nb1 - 192) * 256 + t;          // (nt*16+kt)*64+lane, nt<8, kt<16
        int lane = g & 63, kt = (g >> 6) & 15, nt = g >> 10;
        int ncol = nt * 16 + (lane & 15);
        int k0 = kt * 32 + ((lane >> 4) << 3);
        unsigned short o[8];
        #pragma unroll
        for (int j = 0; j < 8; ++j) o[j] = f2bf(Wlin[(size_t)(k0 + j) * 128 + ncol]);
        *(uint4*)&Wlfrag[(size_t)g * 8] = *(uint4*)o;
    } else if (b < nb1 + 234) {                     // bcat[2560]
        int c = (b - nb1 - 224) * 256 + t;
        if (c < 2560)
            bcat[c] = (c < 512) ? bq[c] * SCALE : (c < 1024) ? bk[c - 512]
                     : (c < 1536) ? bv[c - 1024] : (c < 2048) ? bs[c - 1536] : bqe[c - 2048];
    } else {                                        // deg_count
        int e = (b - nb1 - 234) * 256 + t;
        if (e < E) atomicAdd(&deg[ei[E + e]], 1);
    }
}

// ---------------- K2: exclusive scan of deg -> row_start, cursor ----------------
__global__ __launch_bounds__(1024) void scan_k(const int* __restrict__ deg,
                                               int* __restrict__ row_start,
                                               int* __restrict__ cursor, int n)
{
    __shared__ int part[1024];
    const int t = threadIdx.x;
    const int c0 = t * 16;                  // supports n <= 16384
    int loc[16];
    int s = 0;
    #pragma unroll
    for (int i = 0; i < 16; ++i) {
        int idx = c0 + i;
        int dv = (idx < n) ? deg[idx] : 0;
        loc[i] = s; s += dv;
    }
    part[t] = s;
    __syncthreads();
    int incl = s;
    for (int off = 1; off < 1024; off <<= 1) {
        int other = (t >= off) ? part[t - off] : 0;
        __syncthreads();
        incl += other;
        part[t] = incl;
        __syncthreads();
    }
    const int base = incl - s;
    #pragma unroll
    for (int i = 0; i < 16; ++i) {
        int idx = c0 + i;
        if (idx < n) { row_start[idx] = base + loc[i]; cursor[idx] = base + loc[i]; }
    }
    if (t == 1023) row_start[n] = incl;
}

// ---------------- K3: node GEMM (bf16 MFMA) + LDS-transposed coalesced epilogue ----------
// skip -> qs_bf bf16 [n][512]; q,k,v,qe -> kvq bf16 [n][2048]. + CSR scatter slice (by==40)
__global__ __launch_bounds__(256) void node_gemm_mfma(
    const unsigned short* __restrict__ x_bf, const unsigned short* __restrict__ Wfrag,
    const float* __restrict__ bcat, unsigned short* __restrict__ qs_bf,
    unsigned short* __restrict__ kvq,
    const int* __restrict__ ei, int* __restrict__ cursor, int2* __restrict__ csr,
    int E, int n)
{
    if (blockIdx.y == 40) {                         // scatter slice
        const int nth = gridDim.x * 256;
        for (int e = blockIdx.x * 256 + threadIdx.x; e < E; e += nth) {
            int dnode = ei[E + e];
            int p = atomicAdd(&cursor[dnode], 1);
            csr[p] = make_int2(e, ei[e]);           // (eid, src)
        }
        return;
    }
    __shared__ float tile[64][68];                  // f32 block tile, +4 pad
    const int t = threadIdx.x, lane = t & 63, w = t >> 6;
    const int bm = blockIdx.x * 64;
    const int by = blockIdx.y;
    const int m0 = (w >> 1) * 32;                   // wave-local row base
    const int n0 = (w & 1) * 32;                    // wave-local col base
    const int lr = lane & 15, lk = (lane >> 4) << 3;
    f32x4 acc[2][2] = {};
    #pragma unroll
    for (int kt = 0; kt < 4; ++kt) {
        bf16x8 a[2], bf[2];
        #pragma unroll
        for (int mi = 0; mi < 2; ++mi) {
            int row = bm + m0 + mi * 16 + lr; row = row < n ? row : n - 1;
            a[mi] = *(const bf16x8*)&x_bf[(size_t)row * 128 + kt * 32 + lk];
        }
        #pragma unroll
        for (int ni = 0; ni < 2; ++ni) {
            int nt = (by * 64 + n0 + ni * 16) >> 4;
            bf[ni] = *(const bf16x8*)&Wfrag[(size_t)((nt * 4 + kt) * 64 + lane) * 8];
        }
        #pragma unroll
        for (int mi = 0; mi < 2; ++mi)
            #pragma unroll
            for (int ni = 0; ni < 2; ++ni)
                acc[mi][ni] = __builtin_amdgcn_mfma_f32_16x16x32_bf16(a[mi], bf[ni], acc[mi][ni], 0, 0, 0);
    }
    // stage D-fragments to LDS (layout: col=lane&15, row=(lane>>4)*4+j)
    #pragma unroll
    for (int mi = 0; mi < 2; ++mi)
        #pragma unroll
        for (int j = 0; j < 4; ++j)
            #pragma unroll
            for (int ni = 0; ni < 2; ++ni)
                tile[m0 + mi * 16 + (lane >> 4) * 4 + j][n0 + ni * 16 + lr] = acc[mi][ni][j];
    __syncthreads();
    // coalesced store: thread t -> row r=t>>2, 16 consecutive cols at (t&3)*16
    const int r = t >> 2, cs = (t & 3) * 16;
    const int row = bm + r;
    if (row < n) {
        const int colg0 = by * 64 + cs;
        unsigned short o[16];
        #pragma unroll
        for (int i = 0; i < 16; ++i) o[i] = f2bf(tile[r][cs + i] + bcat[colg0 + i]);
        unsigned short* dst;
        if (by < 24)      dst = &kvq[(size_t)row * 2048 + colg0];            // q,k,v
        else if (by < 32) dst = &qs_bf[(size_t)row * 512 + (colg0 - 1536)];  // skip
        else              dst = &kvq[(size_t)row * 2048 + (colg0 - 512)];    // qe
        *(uint4*)dst = *(uint4*)o;
        *(uint4*)(dst + 8) = *(uint4*)&o[8];
    }
}

// ---------------- K5: flash-style edge phase, 2 waves/node + LDS merge ----------------
// unroll-2 + 1-deep software pipeline; float2-packed math (v_pk_fma_f32);
// non-temporal ea loads (streamed once). launch_bounds (256,4): VGPR=64 optimum —
// (256,8) forces VGPR=32 and spills ~1.9 GB scratch (R18), 8x slower.
__global__ __launch_bounds__(256, 4) void edge_k(
    const unsigned short* __restrict__ kvq, const float* __restrict__ ea,
    const float* __restrict__ be,
    const int* __restrict__ row_start, const int2* __restrict__ csr,
    unsigned short* __restrict__ wsum_bf, unsigned short* __restrict__ vacc_bf, int n)
{
    const int t = threadIdx.x, lane = t & 63, w = t >> 6;
    const int slot = w >> 1, half = w & 1;
    const int node = blockIdx.x * 2 + slot;
    const bool nvalid = node < n;
    const int nodec = nvalid ? node : 0;
    const int g = lane >> 4;            // head
    const int l15 = lane & 15;
    const int sl = l15 * 8;             // dim slice within head

    __shared__ float lds_m[2][4], lds_den[2][4];
    __shared__ float lds_va[2][4][128], lds_ws[2][4][128];

    int rs = 0, deg = 0;
    if (nvalid) { rs = row_start[node]; deg = row_start[node + 1] - rs; }
    const int dh = (deg + 1) >> 1;
    const int lo = half ? dh : 0;
    const int myc = half ? (deg - dh) : dh;

    // per-lane q_s, qe_s as f32x2 pairs (pre-scaled, from bf16)
    f32x2 q2[4], qe2[4];
    {
        const u32x4 uq  = *(const u32x4*)&kvq[(size_t)nodec * 2048 + g * 128 + sl];
        const u32x4 uqe = *(const u32x4*)&kvq[(size_t)nodec * 2048 + 1536 + g * 128 + sl];
        #pragma unroll
        for (int j = 0; j < 4; ++j) { q2[j] = bfpair2f(uq[j]); qe2[j] = bfpair2f(uqe[j]); }
    }
    float qbe;
    {
        const f32x2* bp = (const f32x2*)&be[g * 128 + sl];
        f32x2 pb2 = q2[0] * bp[0] + q2[1] * bp[1] + q2[2] * bp[2] + q2[3] * bp[3];
        float pb = pb2[0] + pb2[1];
        #pragma unroll
        for (int o = 1; o <= 8; o <<= 1) pb += __shfl_xor(pb, o);
        qbe = pb;
    }

    float m = -3.0e38f, den = 0.f;
    f32x2 va2[4] = {}, ws2[4] = {};

    for (int j0 = 0; j0 < myc; j0 += 64) {
        const int cnt = min(64, myc - j0);
        int2 my = make_int2(0, 0);
        if (lane < cnt) my = csr[rs + lo + j0 + lane];

        // ---- preload pair 0 (current register set)
        fv4 cA0, cB0, cA1, cB1; u32x4 cK0, cV0, cK1, cV1;
        {
            const int i1 = (1 < cnt) ? 1 : 0;
            const int e0 = __shfl(my.x, 0), s0_ = __shfl(my.y, 0);
            const int e1 = __shfl(my.x, i1), s1_ = __shfl(my.y, i1);
            const float* ep0 = &ea[(size_t)e0 * 128 + sl];
            const float* ep1 = &ea[(size_t)e1 * 128 + sl];
            cA0 = ntload4(ep0); cB0 = ntload4(ep0 + 4);
            cA1 = ntload4(ep1); cB1 = ntload4(ep1 + 4);
            cK0 = *(const u32x4*)&kvq[(size_t)s0_ * 2048 + 512 + g * 128 + sl];
            cV0 = *(const u32x4*)&kvq[(size_t)s0_ * 2048 + 1024 + g * 128 + sl];
            cK1 = *(const u32x4*)&kvq[(size_t)s1_ * 2048 + 512 + g * 128 + sl];
            cV1 = *(const u32x4*)&kvq[(size_t)s1_ * 2048 + 1024 + g * 128 + sl];
        }

        for (int jj = 0; jj < cnt; jj += 2) {
            // ---- issue next pair's loads (hide latency under current compute)
            fv4 nA0, nB0, nA1, nB1; u32x4 nK0, nV0, nK1, nV1;
            {
                const int nj = (jj + 2 < cnt) ? jj + 2 : jj;        // clamped; unused on exit
                const int i1 = (nj + 1 < cnt) ? nj + 1 : nj;
                const int e0 = __shfl(my.x, nj), s0_ = __shfl(my.y, nj);
                const int e1 = __shfl(my.x, i1), s1_ = __shfl(my.y, i1);
                const float* ep0 = &ea[(size_t)e0 * 128 + sl];
                const float* ep1 = &ea[(size_t)e1 * 128 + sl];
                nA0 = ntload4(ep0); nB0 = ntload4(ep0 + 4);
                nA1 = ntload4(ep1); nB1 = ntload4(ep1 + 4);
                nK0 = *(const u32x4*)&kvq[(size_t)s0_ * 2048 + 512 + g * 128 + sl];
                nV0 = *(const u32x4*)&kvq[(size_t)s0_ * 2048 + 1024 + g * 128 + sl];
                nK1 = *(const u32x4*)&kvq[(size_t)s1_ * 2048 + 512 + g * 128 + sl];
                nV1 = *(const u32x4*)&kvq[(size_t)s1_ * 2048 + 1024 + g * 128 + sl];
            }
            // ---- compute with current pair (float2-packed)
            const bool two = (jj + 1 < cnt);
            f32x2 ef0[4], ef1[4], kf0[4], kf1[4];
            ef0[0][0]=cA0.x; ef0[0][1]=cA0.y; ef0[1][0]=cA0.z; ef0[1][1]=cA0.w;
            ef0[2][0]=cB0.x; ef0[2][1]=cB0.y; ef0[3][0]=cB0.z; ef0[3][1]=cB0.w;
            ef1[0][0]=cA1.x; ef1[0][1]=cA1.y; ef1[1][0]=cA1.z; ef1[1][1]=cA1.w;
            ef1[2][0]=cB1.x; ef1[2][1]=cB1.y; ef1[3][0]=cB1.z; ef1[3][1]=cB1.w;
            #pragma unroll
            for (int j = 0; j < 4; ++j) { kf0[j] = bfpair2f(cK0[j]); kf1[j] = bfpair2f(cK1[j]); }
            f32x2 acc0 = {0.f, 0.f}, acc1 = {0.f, 0.f};
            #pragma unroll
            for (int j = 0; j < 4; ++j) {
                acc0 += q2[j] * kf0[j] + qe2[j] * ef0[j];
                acc1 += q2[j] * kf1[j] + qe2[j] * ef1[j];
            }
            float p0 = acc0[0] + acc0[1];
            float p1 = acc1[0] + acc1[1];
            #pragma unroll
            for (int o = 1; o <= 8; o <<= 1) {
                p0 += __shfl_xor(p0, o);
                p1 += __shfl_xor(p1, o);
            }
            const float a0 = p0 + qbe;
            const float a1 = two ? (p1 + qbe) : -3.0e38f;   // dummy tail: weight 0
            // group-max batched online update (deferred-max THR=8)
            const float gm = fmaxf(a0, a1);
            if (gm > m + 8.f) {
                const float sc = __expf(m - gm);
                den *= sc;
                #pragma unroll
                for (int j = 0; j < 4; ++j) { va2[j] *= sc; ws2[j] *= sc; }
                m = gm;
            }
            const float w0 = __expf(a0 - m);
            const float w1 = __expf(a1 - m);
            den += w0 + w1;
            #pragma unroll
            for (int j = 0; j < 4; ++j) {
                va2[j] += bfpair2f(cV0[j]) * w0 + bfpair2f(cV1[j]) * w1;
                ws2[j] += ef0[j] * w0 + ef1[j] * w1;
            }
            // ---- rotate pipeline registers
            cA0 = nA0; cB0 = nB0; cA1 = nA1; cB1 = nB1;
            cK0 = nK0; cV0 = nV0; cK1 = nK1; cV1 = nV1;
        }
    }

    // merge halves: half 1 publishes, half 0 combines and writes out
    if (half == 1) {
        if (l15 == 0) { lds_m[slot][g] = m; lds_den[slot][g] = den; }
        #pragma unroll
        for (int j = 0; j < 4; ++j) {
            *(f32x2*)&lds_va[slot][g][sl + 2 * j] = va2[j];
            *(f32x2*)&lds_ws[slot][g][sl + 2 * j] = ws2[j];
        }
    }
    __syncthreads();
    if (half == 0 && nvalid) {
        const float m1 = lds_m[slot][g], den1 = lds_den[slot][g];
        const float M = fmaxf(m, m1);
        const float s0 = __expf(m - M), s1 = __expf(m1 - M);
        const float dtot = den * s0 + den1 * s1;
        const float rden = (dtot > 0.f) ? 1.f / dtot : 0.f;
        unsigned short vo[8], wo[8];
        #pragma unroll
        for (int j = 0; j < 4; ++j) {
            f32x2 ov = (va2[j] * s0 + *(const f32x2*)&lds_va[slot][g][sl + 2 * j] * s1) * rden;
            f32x2 ow = (ws2[j] * s0 + *(const f32x2*)&lds_ws[slot][g][sl + 2 * j] * s1) * rden;
            vo[2 * j] = f2bf(ov[0]); vo[2 * j + 1] = f2bf(ov[1]);
            wo[2 * j] = f2bf(ow[0]); wo[2 * j + 1] = f2bf(ow[1]);
        }
        *(uint4*)&vacc_bf[(size_t)node * 512 + g * 128 + sl] = *(uint4*)vo;
        *(uint4*)&wsum_bf[(size_t)node * 512 + g * 128 + sl] = *(uint4*)wo;
    }
}

// ---------------- K6: fused tail (8 waves): y = vacc + wsum@We_h + hb*be + skip; LN;
// out-GEMM; ELU. 16 rows/block. Stage 1: wave (h=w&3, half=w>>2) computes 4 ni-tiles of
// head h. Stage 2: wave w computes out cols [w*16, w*16+16).
__global__ __launch_bounds__(512) void tail_k(
    const unsigned short* __restrict__ wsum_bf, const unsigned short* __restrict__ Wefrag,
    const float* __restrict__ be, const unsigned short* __restrict__ vacc_bf,
    const unsigned short* __restrict__ qs_bf, const int* __restrict__ row_start,
    const unsigned short* __restrict__ Wlfrag, const float* __restrict__ lng,
    const float* __restrict__ lnb, const float* __restrict__ blin,
    const float* __restrict__ x, float* __restrict__ out, int n)
{
    const int t = threadIdx.x, lane = t & 63, w = t >> 6;
    const int h = w & 3, hf = w >> 2;               // stage-1 head, ni-half
    const int r0 = blockIdx.x * 16;
    const int lr = lane & 15, lk = (lane >> 4) << 3;
    __shared__ unsigned short nlds[16][520];        // normed bf16, +8 pad (16B-aligned rows)
    __shared__ float red_s[8][16], red_q[8][16], mval[16], rval[16];

    // ---- stage 1: wave (h,hf) computes 16 rows x 64 cols (head h, ni in [hf*4, hf*4+4))
    f32x4 acc[4] = {};
    #pragma unroll
    for (int kt = 0; kt < 4; ++kt) {
        int row = r0 + lr; row = row < n ? row : n - 1;
        bf16x8 a = *(const bf16x8*)&wsum_bf[(size_t)row * 512 + h * 128 + kt * 32 + lk];
        #pragma unroll
        for (int ni = 0; ni < 4; ++ni) {
            bf16x8 bfr = *(const bf16x8*)&Wefrag[(size_t)(((h * 8 + hf * 4 + ni) * 4 + kt) * 64 + lane) * 8];
            acc[ni] = __builtin_amdgcn_mfma_f32_16x16x32_bf16(a, bfr, acc[ni], 0, 0, 0);
        }
    }
    float g8[4], b8[4];
    #pragma unroll
    for (int ni = 0; ni < 4; ++ni) {
        int col = h * 128 + (hf * 4 + ni) * 16 + lr;
        g8[ni] = lng[col]; b8[ni] = lnb[col];
    }
    float sum_[4], sq_[4];
    #pragma unroll
    for (int j = 0; j < 4; ++j) {
        int row = r0 + (lane >> 4) * 4 + j;
        int rowc = row < n ? row : n - 1;
        const float hb = (row_start[rowc + 1] > row_start[rowc]) ? 1.f : 0.f;
        float s = 0.f, q = 0.f;
        #pragma unroll
        for (int ni = 0; ni < 4; ++ni) {
            int col = h * 128 + (hf * 4 + ni) * 16 + lr;
            float y = acc[ni][j] + bf2f(vacc_bf[(size_t)rowc * 512 + col]) + hb * be[col]
                    + bf2f(qs_bf[(size_t)rowc * 512 + col]);
            acc[ni][j] = y;
            s += y; q += y * y;
        }
        sum_[j] = s; sq_[j] = q;
    }
    #pragma unroll
    for (int o = 1; o <= 8; o <<= 1) {
        #pragma unroll
        for (int j = 0; j < 4; ++j) { sum_[j] += __shfl_xor(sum_[j], o); sq_[j] += __shfl_xor(sq_[j], o); }
    }
    if (lr == 0) {
        #pragma unroll
        for (int j = 0; j < 4; ++j) {
            red_s[w][(lane >> 4) * 4 + j] = sum_[j];
            red_q[w][(lane >> 4) * 4 + j] = sq_[j];
        }
    }
    __syncthreads();
    if (t < 16) {
        float S = 0.f, Q = 0.f;
        #pragma unroll
        for (int i = 0; i < 8; ++i) { S += red_s[i][t]; Q += red_q[i][t]; }
        float mu = S * (1.f / 512.f);
        float var = Q * (1.f / 512.f) - mu * mu;
        mval[t] = mu;
        rval[t] = rsqrtf(fmaxf(var, 0.f) + 1e-5f);
    }
    __syncthreads();
    #pragma unroll
    for (int j = 0; j < 4; ++j) {
        int rowl = (lane >> 4) * 4 + j;
        float mu = mval[rowl], rv = rval[rowl];
        #pragma unroll
        for (int ni = 0; ni < 4; ++ni) {
            int col = h * 128 + (hf * 4 + ni) * 16 + lr;
            nlds[rowl][col] = f2bf((acc[ni][j] - mu) * rv * g8[ni] + b8[ni]);
        }
    }
    __syncthreads();
    // ---- stage 2: out = elu(nlds @ Wlin + blin + x), wave w covers cols [w*16, w*16+16)
    f32x4 acc2 = {};
    #pragma unroll
    for (int kt = 0; kt < 16; ++kt) {
        bf16x8 a2 = *(const bf16x8*)&nlds[lr][kt * 32 + lk];
        bf16x8 bfr = *(const bf16x8*)&Wlfrag[(size_t)((w * 16 + kt) * 64 + lane) * 8];
        acc2 = __builtin_amdgcn_mfma_f32_16x16x32_bf16(a2, bfr, acc2, 0, 0, 0);
    }
    #pragma unroll
    for (int j = 0; j < 4; ++j) {
        int row = r0 + (lane >> 4) * 4 + j;
        if (row < n) {
            int col = w * 16 + lr;
            float z = acc2[j] + blin[col] + x[(size_t)row * 128 + col];
            out[(size_t)row * 128 + col] = z > 0.f ? z : expm1f(z);
        }
    }
}

extern "C" void kernel_launch(void* const* d_in, const int* in_sizes, int n_in,
                              void* d_out, int out_size, void* d_ws, size_t ws_size,
                              hipStream_t stream)
{
    const float* x   = (const float*)d_in[0];
    const int*   ei  = (const int*)d_in[1];
    const float* ea  = (const float*)d_in[2];
    const float* Wq  = (const float*)d_in[3];
    const float* bq  = (const float*)d_in[4];
    const float* Wk  = (const float*)d_in[5];
    const float* bk  = (const float*)d_in[6];
    const float* Wv  = (const float*)d_in[7];
    const float* bv  = (const float*)d_in[8];
    const float* We  = (const float*)d_in[9];
    const float* be  = (const float*)d_in[10];
    const float* Wsk = (const float*)d_in[11];
    const float* bsk = (const float*)d_in[12];
    const float* lng = (const float*)d_in[13];
    const float* lnb = (const float*)d_in[14];
    const float* Wl  = (const float*)d_in[15];
    const float* bl  = (const float*)d_in[16];
    float* out = (float*)d_out;

    const int n = in_sizes[0] / 128;
    const int E = in_sizes[1] / 2;

    float* WqeT  = (float*)d_ws;                    // 128*512
    float* bqe   = WqeT + 128 * 512;                // 512
    float* bcat  = bqe + 512;                       // 2560
    unsigned short* x_bf    = (unsigned short*)(bcat + 2560);   // n*128
    unsigned short* qs_bf   = x_bf + (size_t)n * 128;           // n*512 (skip)
    unsigned short* wsum_bf = qs_bf + (size_t)n * 512;          // n*512
    unsigned short* vacc_bf = wsum_bf + (size_t)n * 512;        // n*512
    unsigned short* kvq     = vacc_bf + (size_t)n * 512;        // n*2048 (q|k|v|qe)
    unsigned short* Wfrag   = kvq + (size_t)n * 2048;           // 128*2560
    unsigned short* Wefrag  = Wfrag + 128 * 2560;               // 128*512
    unsigned short* Wlfrag  = Wefrag + 128 * 512;               // 512*128
    int2* csr = (int2*)(((uintptr_t)(Wlfrag + 512 * 128) + 7) & ~(uintptr_t)7);  // E pairs
    int* deg       = (int*)(csr + E);
    int* row_start = deg + n;
    int* cursor    = row_start + n + 1;

    const int ndegb = (n + 255) / 256;
    wqe_k<<<65 + ndegb, 256, 0, stream>>>(Wq, bq, We, WqeT, bqe, deg, n);
    const int nb1 = (n * 32 + 255) / 256;           // x-conversion blocks (4 elems/thread)
    const int ndc = (E + 255) / 256;
    prep_k<<<nb1 + 234 + ndc, 256, 0, stream>>>(x, Wq, bq, Wk, bk, Wv, bv, Wsk, bsk, WqeT, bqe,
                                                We, Wl, x_bf, Wfrag, Wefrag, Wlfrag, bcat,
                                                ei, deg, E, n, nb1);
    scan_k<<<1, 1024, 0, stream>>>(deg, row_start, cursor, n);
    dim3 g1((n + 63) / 64, 41);
    node_gemm_mfma<<<g1, 256, 0, stream>>>(x_bf, Wfrag, bcat, qs_bf, kvq, ei, cursor, csr, E, n);
    edge_k<<<(n + 1) / 2, 256, 0, stream>>>(kvq, ea, be, row_start, csr,
                                            wsum_bf, vacc_bf, n);
    tail_k<<<(n + 15) / 16, 512, 0, stream>>>(wsum_bf, Wefrag, be, vacc_bf, qs_bf, row_start,
                                              Wlfrag, lng, lnb, bl, x, out, n);
}